// Round 12
// baseline (334.810 us; speedup 1.0000x reference)
//
#include <hip/hip_runtime.h>
#include <hip/hip_bf16.h>
#include <hip/hip_fp16.h>
#include <math.h>

typedef unsigned short u16;
typedef __attribute__((ext_vector_type(8))) short bf16x8;
typedef __attribute__((ext_vector_type(4))) float f32x4;

#define N_NODES 8192
#define DIM 512
#define KSEL 31
#define NCAND 48
#define CANDCAP 128
#define BANDCAP 32
#define SEG_SIZE 2048
#define NVALID 6144  // cross-segment columns per row
#define BAND_T 4e-5f // band half-width around the 31st fast value

__device__ __forceinline__ float ninf() { return __int_as_float(0xff800000); }

// monotone 16-bit key from f16 bits (larger key <=> larger value)
__device__ __forceinline__ unsigned int f16key(unsigned int h) {
  return (h & 0x8000u) ? (0xFFFFu & ~h) : (h | 0x8000u);
}

#define GLD_LDS16(g, l)                                        \
  __builtin_amdgcn_global_load_lds(                            \
      (const __attribute__((address_space(1))) void*)(g),      \
      (__attribute__((address_space(3))) void*)(l), 16, 0, 0)

// ---------------------------------------------------------------------------
// Kernel 1: emb replicating numpy-f32 bit-exactly (verified R6).
// ---------------------------------------------------------------------------
__global__ __launch_bounds__(256) void prep_kernel(
    const float* __restrict__ feat, const float* __restrict__ w0,
    const float* __restrict__ w1, u16* __restrict__ embh,
    float* __restrict__ embf) {
#pragma clang fp contract(off)
  const int row = blockIdx.x;
  const int t = threadIdx.x;
  __shared__ float hs[DIM];
  __shared__ float partial[32];
  __shared__ float rinv_sh;

  const float2 x = *reinterpret_cast<const float2*>(feat + (size_t)row * DIM + t * 2);
  const float2 a = *reinterpret_cast<const float2*>(w0 + t * 2);
  const float2 b = *reinterpret_cast<const float2*>(w1 + t * 2);
  const float h0 = fmaxf(x.x * a.x, 0.0f) * b.x;
  const float h1 = fmaxf(x.y * a.y, 0.0f) * b.y;
  hs[t * 2] = h0;
  hs[t * 2 + 1] = h1;
  __syncthreads();

  if (t < 32) {
    const int base = (t >> 3) * 128 + (t & 7);
    float v = hs[base];
    float acc = v * v;
    for (int i = 1; i < 16; ++i) {
      v = hs[base + 8 * i];
      const float vv = v * v;
      acc = acc + vv;
    }
    partial[t] = acc;
  }
  __syncthreads();
  if (t == 0) {
    float B[4];
    for (int blk = 0; blk < 4; ++blk) {
      const float* p = &partial[blk * 8];
      B[blk] = ((p[0] + p[1]) + (p[2] + p[3])) + ((p[4] + p[5]) + (p[6] + p[7]));
    }
    const float s = (B[0] + B[1]) + (B[2] + B[3]);
    const float sp = s + 1e-24f;
    const float qf = (float)sqrt((double)sp);
    rinv_sh = (float)(1.0 / (double)qf);
  }
  __syncthreads();
  const float rinv = rinv_sh;
  const float e0 = h0 * rinv;
  const float e1 = h1 * rinv;
  *reinterpret_cast<float2*>(embf + (size_t)row * DIM + t * 2) = make_float2(e0, e1);
  __hip_bfloat162 bb;
  bb.x = __float2bfloat16(e0);
  bb.y = __float2bfloat16(e1);
  *reinterpret_cast<__hip_bfloat162*>(embh + (size_t)row * DIM + t * 2) = bb;
}

// ---------------------------------------------------------------------------
// Kernel 2: ranking sim (bf16 MFMA) -> f16, packed cross-seg columns.
// ---------------------------------------------------------------------------
__global__ __launch_bounds__(256) void gemm_kernel(const u16* __restrict__ embh,
                                                   __half* __restrict__ simh) {
  __shared__ u16 As[128][64];
  __shared__ u16 Bs[128][64];
  const int tid = threadIdx.x;
  const int lane = tid & 63;
  const int wave = tid >> 6;
  const int wm = wave >> 1;
  const int wn = wave & 1;
  const int rowTile = blockIdx.y;
  const int segTileBase = (rowTile >> 4) << 4;
  const int cT = blockIdx.x;
  const int colTile = cT < segTileBase ? cT : cT + 16;
  const int row0 = rowTile * 128;
  const int col0 = colTile * 128;

  f32x4 acc[4][4] = {};

  for (int k0 = 0; k0 < DIM; k0 += 64) {
#pragma unroll
    for (int i = 0; i < 4; ++i) {
      const int flat = i * 256 + tid;
      const int r = flat >> 3;
      const int c = (flat & 7) * 8;
      GLD_LDS16(embh + (size_t)(row0 + r) * DIM + k0 + c, &As[r][c]);
      GLD_LDS16(embh + (size_t)(col0 + r) * DIM + k0 + c, &Bs[r][c]);
    }
    __syncthreads();
#pragma unroll
    for (int kk = 0; kk < 2; ++kk) {
      bf16x8 afr[4], bfr[4];
      const int koff = kk * 32 + (lane >> 4) * 8;
      const int rsel = lane & 15;
#pragma unroll
      for (int m = 0; m < 4; ++m)
        afr[m] = *reinterpret_cast<const bf16x8*>(&As[wm * 64 + m * 16 + rsel][koff]);
#pragma unroll
      for (int n = 0; n < 4; ++n)
        bfr[n] = *reinterpret_cast<const bf16x8*>(&Bs[wn * 64 + n * 16 + rsel][koff]);
#pragma unroll
      for (int m = 0; m < 4; ++m)
#pragma unroll
        for (int n = 0; n < 4; ++n)
          acc[m][n] = __builtin_amdgcn_mfma_f32_16x16x32_bf16(afr[m], bfr[n],
                                                              acc[m][n], 0, 0, 0);
    }
    __syncthreads();
  }
#pragma unroll
  for (int m = 0; m < 4; ++m)
#pragma unroll
    for (int n = 0; n < 4; ++n)
#pragma unroll
      for (int j = 0; j < 4; ++j) {
        const int r = row0 + wm * 64 + m * 16 + (lane >> 4) * 4 + j;
        const int pcol = cT * 128 + wn * 64 + n * 16 + (lane & 15);
        simh[(size_t)r * NVALID + pcol] = __float2half(acc[m][n][j]);
      }
}

// ---------------------------------------------------------------------------
// Kernel 3: per-row selection. No row staging (L2 re-reads); ballot-aggregated
// pass-0 histogram (clustered keys); padded per-wave hist copies; parallel
// rank for m31. Membership: fast f32 dots + BAND_T band + bit-exact
// np-sequential recompute in the band (rare). Emits 31 x (col, relu(val)).
// ---------------------------------------------------------------------------
__global__ __launch_bounds__(256) void select_kernel(
    const __half* __restrict__ simh, const float* __restrict__ embf,
    int2* __restrict__ compact) {
  const int row = blockIdx.x;
  const int t = threadIdx.x;
  const int lane = t & 63;
  const int wave = t >> 6;

  __shared__ __align__(16) float er[DIM];
  __shared__ unsigned int hist[2][4][257];
  __shared__ unsigned int above_s, prefix_s;
  __shared__ int ccount_s;
  __shared__ int cidx[CANDCAP];
  __shared__ float cval[CANDCAP];
  __shared__ int bslotof[CANDCAP];
  __shared__ int bandidx[BANDCAP];
  __shared__ float bandex[BANDCAP];
  __shared__ int bandsel[BANDCAP];
  __shared__ float m31_s;
  __shared__ int nH_s, nB_s, outcnt_s;
  __shared__ int outidx[KSEL];
  __shared__ float outval[KSEL];

  const int segBase = (row >> 11) << 11;
  const u16* srow = reinterpret_cast<const u16*>(simh + (size_t)row * NVALID);

  // init: er + zero both hist buffers
  if (t < 128)
    reinterpret_cast<float4*>(er)[t] =
        reinterpret_cast<const float4*>(embf + (size_t)row * DIM)[t];
  {
    unsigned int* hf = &hist[0][0][0];
    for (int z = t; z < 2 * 4 * 257; z += 256) hf[z] = 0;
  }
  for (int c = t; c < CANDCAP; c += 256) bslotof[c] = -1;
  if (t < KSEL) { outidx[t] = segBase; outval[t] = 0.0f; }
  if (t == 0) { above_s = 0; prefix_s = 0; ccount_s = 0; nH_s = 0; nB_s = 0; outcnt_s = 0; }
  __syncthreads();

  // pass 0: upper-byte histogram, ballot-aggregated (keys are clustered)
  for (int r = 0; r < NVALID / 256; ++r) {
    const unsigned int k = f16key(srow[r * 256 + t]);
    const unsigned int bin = k >> 8;
    unsigned long long act = __ballot(1);
    while (act) {
      const int leader = (int)(__ffsll((unsigned long long)act) - 1);
      const unsigned int lb = __shfl(bin, leader, 64);
      const unsigned long long eq = __ballot(bin == lb) & act;
      if (lane == leader)
        atomicAdd(&hist[0][wave][lb], (unsigned int)__popcll(eq));
      act &= ~eq;
    }
  }
  __syncthreads();
  // reduce pass 0
  if (wave == 0) {
    const int x = lane * 4;
    unsigned int b0 = 0, b1 = 0, b2 = 0, b3 = 0;
#pragma unroll
    for (int z = 0; z < 4; ++z) {
      b0 += hist[0][z][x]; b1 += hist[0][z][x + 1];
      b2 += hist[0][z][x + 2]; b3 += hist[0][z][x + 3];
    }
    const unsigned int tot = b0 + b1 + b2 + b3;
    unsigned int inc = tot;
#pragma unroll
    for (int off = 1; off < 64; off <<= 1) {
      const unsigned int v = __shfl_down(inc, off, 64);
      if (lane + off < 64) inc += v;
    }
    const unsigned int exc = inc - tot;
    const unsigned int need = NCAND;
    const unsigned int g3 = exc;
    const unsigned int g2 = g3 + b3;
    const unsigned int g1 = g2 + b2;
    const unsigned int g0 = g1 + b1;
    int sel = -1;
    unsigned int gsel = 0;
    if (g3 < need && g3 + b3 >= need) { sel = x + 3; gsel = g3; }
    else if (g2 < need && g2 + b2 >= need) { sel = x + 2; gsel = g2; }
    else if (g1 < need && g1 + b1 >= need) { sel = x + 1; gsel = g1; }
    else if (g0 < need && g0 + b0 >= need) { sel = x;     gsel = g0; }
    if (sel >= 0) { prefix_s = (unsigned int)sel; above_s = gsel; }
  }
  __syncthreads();

  // pass 1: lower-byte histogram among prefix-matching elements (spread bins)
  {
    const unsigned int pref = prefix_s;
    for (int r = 0; r < NVALID / 256; ++r) {
      const unsigned int k = f16key(srow[r * 256 + t]);
      if ((k >> 8) == pref) atomicAdd(&hist[1][wave][k & 0xFFu], 1u);
    }
  }
  __syncthreads();
  // reduce pass 1
  if (wave == 0) {
    const int x = lane * 4;
    unsigned int b0 = 0, b1 = 0, b2 = 0, b3 = 0;
#pragma unroll
    for (int z = 0; z < 4; ++z) {
      b0 += hist[1][z][x]; b1 += hist[1][z][x + 1];
      b2 += hist[1][z][x + 2]; b3 += hist[1][z][x + 3];
    }
    const unsigned int tot = b0 + b1 + b2 + b3;
    unsigned int inc = tot;
#pragma unroll
    for (int off = 1; off < 64; off <<= 1) {
      const unsigned int v = __shfl_down(inc, off, 64);
      if (lane + off < 64) inc += v;
    }
    const unsigned int exc = inc - tot;
    const unsigned int need = NCAND - above_s;
    const unsigned int g3 = exc;
    const unsigned int g2 = g3 + b3;
    const unsigned int g1 = g2 + b2;
    const unsigned int g0 = g1 + b1;
    int sel = -1;
    if (g3 < need && g3 + b3 >= need) sel = x + 3;
    else if (g2 < need && g2 + b2 >= need) sel = x + 2;
    else if (g1 < need && g1 + b1 >= need) sel = x + 1;
    else if (g0 < need && g0 + b0 >= need) sel = x;
    if (sel >= 0) prefix_s = (prefix_s << 8) | (unsigned int)sel;
  }
  __syncthreads();

  // collect candidates (key >= boundary)
  const unsigned int pfin = prefix_s;
  for (int r = 0; r < NVALID / 256; ++r) {
    const int i = r * 256 + t;
    if (f16key(srow[i]) >= pfin) {
      const int slot = atomicAdd(&ccount_s, 1);
      if (slot < CANDCAP) cidx[slot] = (i < segBase ? i : i + SEG_SIZE);
    }
  }
  __syncthreads();
  const int C = min(ccount_s, CANDCAP);

  // fast wave-parallel f32 dots
  {
    const float4* e4 = reinterpret_cast<const float4*>(er);
    const float4 ea = e4[lane * 2];
    const float4 eb4 = e4[lane * 2 + 1];
    for (int c = wave; c < C; c += 4) {
      const float4* gp = reinterpret_cast<const float4*>(embf + (size_t)cidx[c] * DIM);
      const float4 p0 = gp[lane * 2];
      const float4 p1 = gp[lane * 2 + 1];
      float s = p0.x * ea.x + p0.y * ea.y + p0.z * ea.z + p0.w * ea.w +
                p1.x * eb4.x + p1.y * eb4.y + p1.z * eb4.z + p1.w * eb4.w;
#pragma unroll
      for (int o = 32; o > 0; o >>= 1) s += __shfl_xor(s, o, 64);
      if (lane == 0) cval[c] = s;
    }
  }
  __syncthreads();

  // m31 = 31st largest fast value via parallel rank
  if (t < C) {
    const float v = cval[t];
    int rank = 0;
    for (int j = 0; j < C; ++j) {
      const float oj = cval[j];
      rank += (oj > v || (oj == v && j < t)) ? 1 : 0;
    }
    if (rank == KSEL - 1) m31_s = v;
  }
  __syncthreads();
  const float m = m31_s;

  // classify into definite-in / ambiguous band
  for (int c = t; c < C; c += 256) {
    const float v = cval[c];
    if (v > m + BAND_T) {
      atomicAdd(&nH_s, 1);
    } else if (v >= m - BAND_T) {
      const int slot = atomicAdd(&nB_s, 1);
      if (slot < BANDCAP) { bandidx[slot] = c; bslotof[c] = slot; }
    }
  }
  __syncthreads();
  const int nH = nH_s;
  const int nB = min(nB_s, BANDCAP);
  const int slots = KSEL - nH;
  const bool rare = (nB != slots);

  // rare: bit-exact np-sequential dots for band members
  if (rare && t < nB) {
#pragma clang fp contract(off)
    const float4* g4 = reinterpret_cast<const float4*>(embf + (size_t)cidx[bandidx[t]] * DIM);
    const float4* e4 = reinterpret_cast<const float4*>(er);
    float acc = 0.0f;
    for (int k4 = 0; k4 < DIM / 4; ++k4) {
      const float4 a = e4[k4];
      const float4 b = g4[k4];
      acc = acc + a.x * b.x;
      acc = acc + a.y * b.y;
      acc = acc + a.z * b.z;
      acc = acc + a.w * b.w;
    }
    bandex[t] = acc;
  }
  __syncthreads();
  if (rare && wave == 0 && lane < nB) {
    const float ev = bandex[lane];
    const int ei = cidx[bandidx[lane]];
    int rank = 0;
    for (int j = 0; j < nB; ++j) {
      const float oj = bandex[j];
      const int ij = cidx[bandidx[j]];
      if (oj > ev || (oj == ev && ij < ei)) rank++;
    }
    bandsel[lane] = (rank < slots) ? 1 : 0;
  }
  __syncthreads();

  // emit kept candidates compactly
  for (int c = t; c < C; c += 256) {
    const float v = cval[c];
    bool k = (v > m + BAND_T);
    if (!k) {
      const int bs = bslotof[c];
      if (bs >= 0) k = rare ? (bandsel[bs] != 0) : true;
    }
    if (k) {
      const int slot = atomicAdd(&outcnt_s, 1);
      if (slot < KSEL) { outidx[slot] = cidx[c]; outval[slot] = fmaxf(v, 0.0f); }
    }
  }
  __syncthreads();
  if (t < KSEL)
    compact[(size_t)row * KSEL + t] = make_int2(outidx[t], __float_as_int(outval[t]));
}

// ---------------------------------------------------------------------------
// Kernel 4: streaming writer — zero full row, scatter 31 values.
// ---------------------------------------------------------------------------
__global__ __launch_bounds__(256) void write_kernel(
    const int2* __restrict__ compact, float* __restrict__ out) {
  const int row = blockIdx.x;
  const int t = threadIdx.x;
  __shared__ int sidx[KSEL];
  __shared__ float sval[KSEL];
  if (t < KSEL) {
    const int2 e = compact[(size_t)row * KSEL + t];
    sidx[t] = e.x;
    sval[t] = __int_as_float(e.y);
  }
  float* orow = out + (size_t)row * N_NODES;
  const float4 zero4 = make_float4(0.f, 0.f, 0.f, 0.f);
  __syncthreads();
#pragma unroll
  for (int i = 0; i < 8; ++i)
    reinterpret_cast<float4*>(orow)[i * 256 + t] = zero4;
  __syncthreads();
  if (t < KSEL) orow[sidx[t]] = sval[t];
}

// ---------------------------------------------------------------------------
extern "C" void kernel_launch(void* const* d_in, const int* in_sizes, int n_in,
                              void* d_out, int out_size, void* d_ws, size_t ws_size,
                              hipStream_t stream) {
  const float* feat = (const float*)d_in[0];
  const float* w0 = (const float*)d_in[1];
  const float* w1 = (const float*)d_in[2];
  float* out = (float*)d_out;

  u16* embh = (u16*)d_ws;                                           // 8 MB (dead after gemm)
  float* embf = (float*)((char*)d_ws + (size_t)N_NODES * DIM * 2);  // 16 MB
  int2* compact = (int2*)d_ws;                                      // 2 MB, reuses embh region
  __half* simh = (__half*)d_out;                                    // 100 MB packed f16 sims

  prep_kernel<<<N_NODES, 256, 0, stream>>>(feat, w0, w1, embh, embf);
  dim3 grid(48, 64);
  gemm_kernel<<<grid, 256, 0, stream>>>(embh, simh);
  select_kernel<<<N_NODES, 256, 0, stream>>>(simh, embf, compact);
  write_kernel<<<N_NODES, 256, 0, stream>>>(compact, out);
}

// Round 13
// 297.297 us; speedup vs baseline: 1.1262x; 1.1262x over previous
//
#include <hip/hip_runtime.h>
#include <hip/hip_bf16.h>
#include <hip/hip_fp16.h>
#include <math.h>

typedef unsigned short u16;
typedef unsigned int u32;
typedef __attribute__((ext_vector_type(8))) short bf16x8;
typedef __attribute__((ext_vector_type(4))) float f32x4;

#define N_NODES 8192
#define DIM 512
#define KSEL 31
#define NCAND 48
#define CANDCAP 128
#define BANDCAP 32
#define SEG_SIZE 2048
#define NVALID 6144  // cross-segment columns per row
#define BAND_T 4e-5f // band half-width around the 31st fast value

__device__ __forceinline__ float ninf() { return __int_as_float(0xff800000); }

// monotone 16-bit key from f16 bits (larger key <=> larger value)
__device__ __forceinline__ u32 f16key(u32 h) {
  return (h & 0x8000u) ? (0xFFFFu & ~h) : (h | 0x8000u);
}

#define GLD_LDS16(g, l)                                        \
  __builtin_amdgcn_global_load_lds(                            \
      (const __attribute__((address_space(1))) void*)(g),      \
      (__attribute__((address_space(3))) void*)(l), 16, 0, 0)

// ---------------------------------------------------------------------------
// Kernel 1: emb replicating numpy-f32 bit-exactly (verified R6).
// ---------------------------------------------------------------------------
__global__ __launch_bounds__(256) void prep_kernel(
    const float* __restrict__ feat, const float* __restrict__ w0,
    const float* __restrict__ w1, u16* __restrict__ embh,
    float* __restrict__ embf) {
#pragma clang fp contract(off)
  const int row = blockIdx.x;
  const int t = threadIdx.x;
  __shared__ float hs[DIM];
  __shared__ float partial[32];
  __shared__ float rinv_sh;

  const float2 x = *reinterpret_cast<const float2*>(feat + (size_t)row * DIM + t * 2);
  const float2 a = *reinterpret_cast<const float2*>(w0 + t * 2);
  const float2 b = *reinterpret_cast<const float2*>(w1 + t * 2);
  const float h0 = fmaxf(x.x * a.x, 0.0f) * b.x;
  const float h1 = fmaxf(x.y * a.y, 0.0f) * b.y;
  hs[t * 2] = h0;
  hs[t * 2 + 1] = h1;
  __syncthreads();

  if (t < 32) {
    const int base = (t >> 3) * 128 + (t & 7);
    float v = hs[base];
    float acc = v * v;
    for (int i = 1; i < 16; ++i) {
      v = hs[base + 8 * i];
      const float vv = v * v;
      acc = acc + vv;
    }
    partial[t] = acc;
  }
  __syncthreads();
  if (t == 0) {
    float B[4];
    for (int blk = 0; blk < 4; ++blk) {
      const float* p = &partial[blk * 8];
      B[blk] = ((p[0] + p[1]) + (p[2] + p[3])) + ((p[4] + p[5]) + (p[6] + p[7]));
    }
    const float s = (B[0] + B[1]) + (B[2] + B[3]);
    const float sp = s + 1e-24f;
    const float qf = (float)sqrt((double)sp);
    rinv_sh = (float)(1.0 / (double)qf);
  }
  __syncthreads();
  const float rinv = rinv_sh;
  const float e0 = h0 * rinv;
  const float e1 = h1 * rinv;
  *reinterpret_cast<float2*>(embf + (size_t)row * DIM + t * 2) = make_float2(e0, e1);
  __hip_bfloat162 bb;
  bb.x = __float2bfloat16(e0);
  bb.y = __float2bfloat16(e1);
  *reinterpret_cast<__hip_bfloat162*>(embh + (size_t)row * DIM + t * 2) = bb;
}

// ---------------------------------------------------------------------------
// Kernel 2: ranking sim (bf16 MFMA) -> f16, packed cross-seg columns.
// ---------------------------------------------------------------------------
__global__ __launch_bounds__(256) void gemm_kernel(const u16* __restrict__ embh,
                                                   __half* __restrict__ simh) {
  __shared__ u16 As[128][64];
  __shared__ u16 Bs[128][64];
  const int tid = threadIdx.x;
  const int lane = tid & 63;
  const int wave = tid >> 6;
  const int wm = wave >> 1;
  const int wn = wave & 1;
  const int rowTile = blockIdx.y;
  const int segTileBase = (rowTile >> 4) << 4;
  const int cT = blockIdx.x;
  const int colTile = cT < segTileBase ? cT : cT + 16;
  const int row0 = rowTile * 128;
  const int col0 = colTile * 128;

  f32x4 acc[4][4] = {};

  for (int k0 = 0; k0 < DIM; k0 += 64) {
#pragma unroll
    for (int i = 0; i < 4; ++i) {
      const int flat = i * 256 + tid;
      const int r = flat >> 3;
      const int c = (flat & 7) * 8;
      GLD_LDS16(embh + (size_t)(row0 + r) * DIM + k0 + c, &As[r][c]);
      GLD_LDS16(embh + (size_t)(col0 + r) * DIM + k0 + c, &Bs[r][c]);
    }
    __syncthreads();
#pragma unroll
    for (int kk = 0; kk < 2; ++kk) {
      bf16x8 afr[4], bfr[4];
      const int koff = kk * 32 + (lane >> 4) * 8;
      const int rsel = lane & 15;
#pragma unroll
      for (int m = 0; m < 4; ++m)
        afr[m] = *reinterpret_cast<const bf16x8*>(&As[wm * 64 + m * 16 + rsel][koff]);
#pragma unroll
      for (int n = 0; n < 4; ++n)
        bfr[n] = *reinterpret_cast<const bf16x8*>(&Bs[wn * 64 + n * 16 + rsel][koff]);
#pragma unroll
      for (int m = 0; m < 4; ++m)
#pragma unroll
        for (int n = 0; n < 4; ++n)
          acc[m][n] = __builtin_amdgcn_mfma_f32_16x16x32_bf16(afr[m], bfr[n],
                                                              acc[m][n], 0, 0, 0);
    }
    __syncthreads();
  }
#pragma unroll
  for (int m = 0; m < 4; ++m)
#pragma unroll
    for (int n = 0; n < 4; ++n)
#pragma unroll
      for (int j = 0; j < 4; ++j) {
        const int r = row0 + wm * 64 + m * 16 + (lane >> 4) * 4 + j;
        const int pcol = cT * 128 + wn * 64 + n * 16 + (lane & 15);
        simh[(size_t)r * NVALID + pcol] = __float2half(acc[m][n][j]);
      }
}

// ---------------------------------------------------------------------------
// Kernel 3: per-row selection, register-resident row (read once). 2-pass
// radix on f16 key from regs; ballot-aggregated pass-0; fast f32 dots +
// BAND_T band + bit-exact np-sequential recompute in band (rare).
// ---------------------------------------------------------------------------
__global__ __launch_bounds__(256) void select_kernel(
    const __half* __restrict__ simh, const float* __restrict__ embf,
    int2* __restrict__ compact) {
  const int row = blockIdx.x;
  const int t = threadIdx.x;
  const int lane = t & 63;
  const int wave = t >> 6;

  __shared__ __align__(16) float er[DIM];
  __shared__ u32 hist[2][4][257];
  __shared__ u32 above_s, prefix_s;
  __shared__ int ccount_s;
  __shared__ int cidx[CANDCAP];
  __shared__ float cval[CANDCAP];
  __shared__ int bslotof[CANDCAP];
  __shared__ int bandidx[BANDCAP];
  __shared__ float bandex[BANDCAP];
  __shared__ int bandsel[BANDCAP];
  __shared__ float m31_s;
  __shared__ int nH_s, nB_s, outcnt_s;
  __shared__ int outidx[KSEL];
  __shared__ float outval[KSEL];

  const int segBase = (row >> 11) << 11;

  // load row into registers: 3 coalesced uint4 per thread (24 f16 values)
  uint4 q0, q1, q2;
  {
    const uint4* src = reinterpret_cast<const uint4*>(simh + (size_t)row * NVALID);
    q0 = src[t];
    q1 = src[256 + t];
    q2 = src[512 + t];
  }
  if (t < 128)
    reinterpret_cast<float4*>(er)[t] =
        reinterpret_cast<const float4*>(embf + (size_t)row * DIM)[t];
  {
    u32* hf = &hist[0][0][0];
    for (int z = t; z < 2 * 4 * 257; z += 256) hf[z] = 0;
  }
  for (int c = t; c < CANDCAP; c += 256) bslotof[c] = -1;
  if (t < KSEL) { outidx[t] = segBase; outval[t] = 0.0f; }
  if (t == 0) { above_s = 0; prefix_s = 0; ccount_s = 0; nH_s = 0; nB_s = 0; outcnt_s = 0; }
  __syncthreads();

  // extract the 24 keys once (static unroll -> stays in VGPRs)
  u32 key[24];
#pragma unroll
  for (int r = 0; r < 3; ++r) {
    const uint4 q = (r == 0) ? q0 : (r == 1) ? q1 : q2;
    const u32 w[4] = {q.x, q.y, q.z, q.w};
#pragma unroll
    for (int e = 0; e < 8; ++e)
      key[r * 8 + e] = f16key((w[e >> 1] >> (16 * (e & 1))) & 0xFFFFu);
  }

  // pass 0: upper-byte histogram, ballot-aggregated (keys are clustered)
#pragma unroll
  for (int v = 0; v < 24; ++v) {
    const u32 bin = key[v] >> 8;
    unsigned long long act = __ballot(1);
    while (act) {
      const int leader = (int)(__ffsll((unsigned long long)act) - 1);
      const u32 lb = __shfl(bin, leader, 64);
      const unsigned long long eq = __ballot(bin == lb) & act;
      if (lane == leader)
        atomicAdd(&hist[0][wave][lb], (u32)__popcll(eq));
      act &= ~eq;
    }
  }
  __syncthreads();
  // reduce pass 0
  if (wave == 0) {
    const int x = lane * 4;
    u32 b0 = 0, b1 = 0, b2 = 0, b3 = 0;
#pragma unroll
    for (int z = 0; z < 4; ++z) {
      b0 += hist[0][z][x]; b1 += hist[0][z][x + 1];
      b2 += hist[0][z][x + 2]; b3 += hist[0][z][x + 3];
    }
    const u32 tot = b0 + b1 + b2 + b3;
    u32 inc = tot;
#pragma unroll
    for (int off = 1; off < 64; off <<= 1) {
      const u32 v = __shfl_down(inc, off, 64);
      if (lane + off < 64) inc += v;
    }
    const u32 exc = inc - tot;
    const u32 need = NCAND;
    const u32 g3 = exc;
    const u32 g2 = g3 + b3;
    const u32 g1 = g2 + b2;
    const u32 g0 = g1 + b1;
    int sel = -1;
    u32 gsel = 0;
    if (g3 < need && g3 + b3 >= need) { sel = x + 3; gsel = g3; }
    else if (g2 < need && g2 + b2 >= need) { sel = x + 2; gsel = g2; }
    else if (g1 < need && g1 + b1 >= need) { sel = x + 1; gsel = g1; }
    else if (g0 < need && g0 + b0 >= need) { sel = x;     gsel = g0; }
    if (sel >= 0) { prefix_s = (u32)sel; above_s = gsel; }
  }
  __syncthreads();

  // pass 1: lower-byte histogram among prefix-matching keys (from regs)
  {
    const u32 pref = prefix_s;
#pragma unroll
    for (int v = 0; v < 24; ++v)
      if ((key[v] >> 8) == pref) atomicAdd(&hist[1][wave][key[v] & 0xFFu], 1u);
  }
  __syncthreads();
  // reduce pass 1
  if (wave == 0) {
    const int x = lane * 4;
    u32 b0 = 0, b1 = 0, b2 = 0, b3 = 0;
#pragma unroll
    for (int z = 0; z < 4; ++z) {
      b0 += hist[1][z][x]; b1 += hist[1][z][x + 1];
      b2 += hist[1][z][x + 2]; b3 += hist[1][z][x + 3];
    }
    const u32 tot = b0 + b1 + b2 + b3;
    u32 inc = tot;
#pragma unroll
    for (int off = 1; off < 64; off <<= 1) {
      const u32 v = __shfl_down(inc, off, 64);
      if (lane + off < 64) inc += v;
    }
    const u32 exc = inc - tot;
    const u32 need = NCAND - above_s;
    const u32 g3 = exc;
    const u32 g2 = g3 + b3;
    const u32 g1 = g2 + b2;
    const u32 g0 = g1 + b1;
    int sel = -1;
    if (g3 < need && g3 + b3 >= need) sel = x + 3;
    else if (g2 < need && g2 + b2 >= need) sel = x + 2;
    else if (g1 < need && g1 + b1 >= need) sel = x + 1;
    else if (g0 < need && g0 + b0 >= need) sel = x;
    if (sel >= 0) prefix_s = (prefix_s << 8) | (u32)sel;
  }
  __syncthreads();

  // collect candidates from regs (key >= boundary)
  const u32 pfin = prefix_s;
#pragma unroll
  for (int r = 0; r < 3; ++r) {
#pragma unroll
    for (int e = 0; e < 8; ++e) {
      if (key[r * 8 + e] >= pfin) {
        const int i = (r * 256 + t) * 8 + e;  // packed col
        const int slot = atomicAdd(&ccount_s, 1);
        if (slot < CANDCAP) cidx[slot] = (i < segBase ? i : i + SEG_SIZE);
      }
    }
  }
  __syncthreads();
  const int C = min(ccount_s, CANDCAP);

  // fast wave-parallel f32 dots
  {
    const float4* e4 = reinterpret_cast<const float4*>(er);
    const float4 ea = e4[lane * 2];
    const float4 eb4 = e4[lane * 2 + 1];
    for (int c = wave; c < C; c += 4) {
      const float4* gp = reinterpret_cast<const float4*>(embf + (size_t)cidx[c] * DIM);
      const float4 p0 = gp[lane * 2];
      const float4 p1 = gp[lane * 2 + 1];
      float s = p0.x * ea.x + p0.y * ea.y + p0.z * ea.z + p0.w * ea.w +
                p1.x * eb4.x + p1.y * eb4.y + p1.z * eb4.z + p1.w * eb4.w;
#pragma unroll
      for (int o = 32; o > 0; o >>= 1) s += __shfl_xor(s, o, 64);
      if (lane == 0) cval[c] = s;
    }
  }
  __syncthreads();

  // m31 = 31st largest fast value via parallel rank
  if (t < C) {
    const float v = cval[t];
    int rank = 0;
    for (int j = 0; j < C; ++j) {
      const float oj = cval[j];
      rank += (oj > v || (oj == v && j < t)) ? 1 : 0;
    }
    if (rank == KSEL - 1) m31_s = v;
  }
  __syncthreads();
  const float m = m31_s;

  // classify into definite-in / ambiguous band
  for (int c = t; c < C; c += 256) {
    const float v = cval[c];
    if (v > m + BAND_T) {
      atomicAdd(&nH_s, 1);
    } else if (v >= m - BAND_T) {
      const int slot = atomicAdd(&nB_s, 1);
      if (slot < BANDCAP) { bandidx[slot] = c; bslotof[c] = slot; }
    }
  }
  __syncthreads();
  const int nH = nH_s;
  const int nB = min(nB_s, BANDCAP);
  const int slots = KSEL - nH;
  const bool rare = (nB != slots);

  // rare: bit-exact np-sequential dots for band members
  if (rare && t < nB) {
#pragma clang fp contract(off)
    const float4* g4 = reinterpret_cast<const float4*>(embf + (size_t)cidx[bandidx[t]] * DIM);
    const float4* e4 = reinterpret_cast<const float4*>(er);
    float acc = 0.0f;
    for (int k4 = 0; k4 < DIM / 4; ++k4) {
      const float4 a = e4[k4];
      const float4 b = g4[k4];
      acc = acc + a.x * b.x;
      acc = acc + a.y * b.y;
      acc = acc + a.z * b.z;
      acc = acc + a.w * b.w;
    }
    bandex[t] = acc;
  }
  __syncthreads();
  if (rare && wave == 0 && lane < nB) {
    const float ev = bandex[lane];
    const int ei = cidx[bandidx[lane]];
    int rank = 0;
    for (int j = 0; j < nB; ++j) {
      const float oj = bandex[j];
      const int ij = cidx[bandidx[j]];
      if (oj > ev || (oj == ev && ij < ei)) rank++;
    }
    bandsel[lane] = (rank < slots) ? 1 : 0;
  }
  __syncthreads();

  // emit kept candidates compactly
  for (int c = t; c < C; c += 256) {
    const float v = cval[c];
    bool k = (v > m + BAND_T);
    if (!k) {
      const int bs = bslotof[c];
      if (bs >= 0) k = rare ? (bandsel[bs] != 0) : true;
    }
    if (k) {
      const int slot = atomicAdd(&outcnt_s, 1);
      if (slot < KSEL) { outidx[slot] = cidx[c]; outval[slot] = fmaxf(v, 0.0f); }
    }
  }
  __syncthreads();
  if (t < KSEL)
    compact[(size_t)row * KSEL + t] = make_int2(outidx[t], __float_as_int(outval[t]));
}

// ---------------------------------------------------------------------------
// Kernel 4: streaming writer — zero full row, scatter 31 values.
// ---------------------------------------------------------------------------
__global__ __launch_bounds__(256) void write_kernel(
    const int2* __restrict__ compact, float* __restrict__ out) {
  const int row = blockIdx.x;
  const int t = threadIdx.x;
  __shared__ int sidx[KSEL];
  __shared__ float sval[KSEL];
  if (t < KSEL) {
    const int2 e = compact[(size_t)row * KSEL + t];
    sidx[t] = e.x;
    sval[t] = __int_as_float(e.y);
  }
  float* orow = out + (size_t)row * N_NODES;
  const float4 zero4 = make_float4(0.f, 0.f, 0.f, 0.f);
  __syncthreads();
#pragma unroll
  for (int i = 0; i < 8; ++i)
    reinterpret_cast<float4*>(orow)[i * 256 + t] = zero4;
  __syncthreads();
  if (t < KSEL) orow[sidx[t]] = sval[t];
}

// ---------------------------------------------------------------------------
extern "C" void kernel_launch(void* const* d_in, const int* in_sizes, int n_in,
                              void* d_out, int out_size, void* d_ws, size_t ws_size,
                              hipStream_t stream) {
  const float* feat = (const float*)d_in[0];
  const float* w0 = (const float*)d_in[1];
  const float* w1 = (const float*)d_in[2];
  float* out = (float*)d_out;

  u16* embh = (u16*)d_ws;                                           // 8 MB (dead after gemm)
  float* embf = (float*)((char*)d_ws + (size_t)N_NODES * DIM * 2);  // 16 MB
  int2* compact = (int2*)d_ws;                                      // 2 MB, reuses embh region
  __half* simh = (__half*)d_out;                                    // 100 MB packed f16 sims

  prep_kernel<<<N_NODES, 256, 0, stream>>>(feat, w0, w1, embh, embf);
  dim3 grid(48, 64);
  gemm_kernel<<<grid, 256, 0, stream>>>(embh, simh);
  select_kernel<<<N_NODES, 256, 0, stream>>>(simh, embf, compact);
  write_kernel<<<N_NODES, 256, 0, stream>>>(compact, out);
}